// Round 1
// baseline (838.985 us; speedup 1.0000x reference)
//
#include <hip/hip_runtime.h>

#define CN 16
#define HN 128
#define IMH 256
#define IMW 256
#define TW 32
#define TH 8

// ---------------- Pass 1: perception + MLP + stochastic update ----------------
// One thread per pixel. x tile (+1 halo) staged in LDS. Writes x_new to out and
// the channel-3 plane of x_new to ws (needed by pass 2's maxpool with halo).
__global__ __launch_bounds__(256) void nca_pass1(
    const float* __restrict__ x, const float* __restrict__ upd,
    const float* __restrict__ w1, const float* __restrict__ b1,
    const float* __restrict__ w2, float* __restrict__ out,
    float* __restrict__ xn3)
{
    __shared__ float sx[CN][TH + 2][TW + 2];   // 16*10*34*4 = 21.8 KiB
    const int b  = blockIdx.z;
    const int i0 = blockIdx.y * TH;
    const int j0 = blockIdx.x * TW;
    const int tid = threadIdx.x;
    const float* xb = x + (size_t)b * CN * IMH * IMW;

    // stage tile with zero padding (conv pads zeros)
    for (int idx = tid; idx < CN * (TH + 2) * (TW + 2); idx += 256) {
        int c   = idx / ((TH + 2) * (TW + 2));
        int r   = (idx / (TW + 2)) % (TH + 2);
        int col = idx % (TW + 2);
        int gi = i0 + r - 1, gj = j0 + col - 1;
        float v = 0.f;
        if (gi >= 0 && gi < IMH && gj >= 0 && gj < IMW)
            v = xb[(size_t)c * IMH * IMW + gi * IMW + gj];
        sx[c][r][col] = v;
    }
    __syncthreads();

    const int ty = tid >> 5, tx = tid & 31;
    const int i = i0 + ty, j = j0 + tx;

    // perception: y[3c]=identity, y[3c+1]=sobel-x, y[3c+2]=sobel-y
    float y[3 * CN];
#pragma unroll
    for (int c = 0; c < CN; ++c) {
        float a00 = sx[c][ty][tx],     a01 = sx[c][ty][tx + 1],     a02 = sx[c][ty][tx + 2];
        float a10 = sx[c][ty + 1][tx],                              a12 = sx[c][ty + 1][tx + 2];
        float a20 = sx[c][ty + 2][tx], a21 = sx[c][ty + 2][tx + 1], a22 = sx[c][ty + 2][tx + 2];
        float a11 = sx[c][ty + 1][tx + 1];
        y[3 * c]     = a11;
        y[3 * c + 1] = ((a02 - a00) + 2.f * (a12 - a10) + (a22 - a20)) * 0.125f;
        y[3 * c + 2] = ((a20 - a00) + 2.f * (a21 - a01) + (a22 - a02)) * 0.125f;
    }

    float dxv[CN];
#pragma unroll
    for (int c = 0; c < CN; ++c) dxv[c] = 0.f;

    // MLP: 48 -> 128 (ReLU) -> 16, 4 hidden units per iteration (4 indep FMA chains)
    for (int o = 0; o < HN; o += 4) {
        float a0 = b1[o], a1 = b1[o + 1], a2 = b1[o + 2], a3 = b1[o + 3];
#pragma unroll
        for (int c = 0; c < 3 * CN; ++c) {
            float yv = y[c];
            a0 = fmaf(w1[(o + 0) * 48 + c], yv, a0);
            a1 = fmaf(w1[(o + 1) * 48 + c], yv, a1);
            a2 = fmaf(w1[(o + 2) * 48 + c], yv, a2);
            a3 = fmaf(w1[(o + 3) * 48 + c], yv, a3);
        }
        a0 = fmaxf(a0, 0.f); a1 = fmaxf(a1, 0.f);
        a2 = fmaxf(a2, 0.f); a3 = fmaxf(a3, 0.f);
#pragma unroll
        for (int c = 0; c < CN; ++c) {
            float d = dxv[c];
            d = fmaf(w2[c * HN + o],     a0, d);
            d = fmaf(w2[c * HN + o + 1], a1, d);
            d = fmaf(w2[c * HN + o + 2], a2, d);
            d = fmaf(w2[c * HN + o + 3], a3, d);
            dxv[c] = d;
        }
    }

    const float m = (upd[(size_t)b * IMH * IMW + i * IMW + j] <= 0.5f) ? 1.f : 0.f;
    float* ob = out + (size_t)b * CN * IMH * IMW;
#pragma unroll
    for (int c = 0; c < CN; ++c) {
        float xn = fmaf(dxv[c], m, y[3 * c]);   // y[3c] is the identity tap = x center
        ob[(size_t)c * IMH * IMW + i * IMW + j] = xn;
        if (c == 3) xn3[(size_t)b * IMH * IMW + i * IMW + j] = xn;
    }
}

// ---------------- Pass 2: alive masking ----------------
// alive = (maxpool3(x[:,3]) > 0.1) & (maxpool3(x_new[:,3]) > 0.1); zero dead pixels.
// Only own-pixel in-place writes to out -> no inter-block race.
__global__ __launch_bounds__(256) void nca_pass2(
    const float* __restrict__ x, const float* __restrict__ xn3,
    float* __restrict__ out)
{
    __shared__ float s0[TH + 2][TW + 2];
    __shared__ float s1[TH + 2][TW + 2];
    const int b  = blockIdx.z;
    const int i0 = blockIdx.y * TH;
    const int j0 = blockIdx.x * TW;
    const int tid = threadIdx.x;
    const float* x3 = x   + ((size_t)b * CN + 3) * IMH * IMW;
    const float* n3 = xn3 + (size_t)b * IMH * IMW;

    for (int idx = tid; idx < (TH + 2) * (TW + 2); idx += 256) {
        int r = idx / (TW + 2), col = idx % (TW + 2);
        int gi = i0 + r - 1, gj = j0 + col - 1;
        bool in = (gi >= 0 && gi < IMH && gj >= 0 && gj < IMW);
        s0[r][col] = in ? x3[gi * IMW + gj] : -1e30f;   // -inf padding semantics
        s1[r][col] = in ? n3[gi * IMW + gj] : -1e30f;
    }
    __syncthreads();

    const int ty = tid >> 5, tx = tid & 31;
    float m0 = -1e30f, m1 = -1e30f;
#pragma unroll
    for (int di = 0; di < 3; ++di)
#pragma unroll
        for (int dj = 0; dj < 3; ++dj) {
            m0 = fmaxf(m0, s0[ty + di][tx + dj]);
            m1 = fmaxf(m1, s1[ty + di][tx + dj]);
        }
    const bool alive = (m0 > 0.1f) && (m1 > 0.1f);
    if (!alive) {
        const int i = i0 + ty, j = j0 + tx;
        float* ob = out + (size_t)b * CN * IMH * IMW;
#pragma unroll
        for (int c = 0; c < CN; ++c)
            ob[(size_t)c * IMH * IMW + i * IMW + j] = 0.f;
    }
}

extern "C" void kernel_launch(void* const* d_in, const int* in_sizes, int n_in,
                              void* d_out, int out_size, void* d_ws, size_t ws_size,
                              hipStream_t stream) {
    const float* x   = (const float*)d_in[0];
    const float* upd = (const float*)d_in[1];
    const float* w1  = (const float*)d_in[2];
    const float* b1  = (const float*)d_in[3];
    const float* w2  = (const float*)d_in[4];
    float* out = (float*)d_out;
    float* xn3 = (float*)d_ws;   // B*H*W floats = 8 MiB

    dim3 grid(IMW / TW, IMH / TH, 32);
    nca_pass1<<<grid, 256, 0, stream>>>(x, upd, w1, b1, w2, out, xn3);
    nca_pass2<<<grid, 256, 0, stream>>>(x, xn3, out);
}

// Round 2
// 631.958 us; speedup vs baseline: 1.3276x; 1.3276x over previous
//
#include <hip/hip_runtime.h>

#define CN 16
#define HN 128
#define IMH 256
#define IMW 256
#define HW (IMH * IMW)

typedef __attribute__((ext_vector_type(8))) short short8;
typedef __attribute__((ext_vector_type(4))) float float4v;
typedef __attribute__((ext_vector_type(2))) unsigned int uint2v;
typedef __attribute__((ext_vector_type(4))) unsigned int uint4v;

__device__ __forceinline__ unsigned int f2bf(float f) {
    unsigned int u = __builtin_bit_cast(unsigned int, f);
    u += 0x7FFFu + ((u >> 16) & 1u);          // round-to-nearest-even
    return u >> 16;
}
__device__ __forceinline__ unsigned int pack2(float a, float b) {
    return f2bf(a) | (f2bf(b) << 16);
}

// ---------------- Kernel A: perception + MFMA MLP + update ----------------
// 128 pixels per block (4x32 tile), 256 threads = 4 waves.
// GEMM1 (transposed): h^T = w1 * y^T  (M=128 hid, K=48->64, N=128 pix)
// GEMM2:              dx  = h * w2^T  (M=128 pix, K=128,    N=16 ch)
__global__ __launch_bounds__(256) void nca_mfma(
    const float* __restrict__ x, const float* __restrict__ upd,
    const float* __restrict__ w1, const float* __restrict__ b1,
    const float* __restrict__ w2, float* __restrict__ out,
    float* __restrict__ xn3)
{
    __shared__ union {
        float sx[CN][6][34];              // 13056 B  (staging, dead after perception)
        unsigned short h[128][136];       // 34816 B  (h[pix][hid], pitch 272B)
    } u;
    __shared__ unsigned short ybuf[128][72];  // 18432 B  (y[pix][k], pitch 144B)
    __shared__ float xc[128][20];             // 10240 B  (x centers, pitch 80B)
    // total 63488 B

    const int b   = blockIdx.z;
    const int i0  = blockIdx.y * 4;
    const int j0  = blockIdx.x * 32;
    const int tid = threadIdx.x;
    const float* xb = x + (size_t)b * CN * HW;

    // ---- stage x tile (+1 halo, zero padded) ----
    for (int idx = tid; idx < CN * 6 * 34; idx += 256) {
        int c   = idx / (6 * 34);
        int rem = idx - c * (6 * 34);
        int r   = rem / 34;
        int col = rem - r * 34;
        int gi = i0 + r - 1, gj = j0 + col - 1;
        float v = 0.f;
        if ((unsigned)gi < IMH && (unsigned)gj < IMW)
            v = xb[c * HW + gi * IMW + gj];
        u.sx[c][r][col] = v;
    }

    const int lane = tid & 63;
    const int w    = tid >> 6;     // wave id 0..3
    const int l15  = lane & 15;
    const int q    = lane >> 4;    // quad 0..3

    // ---- preload weight fragments (overlaps staging latency) ----
    // GEMM1 A-operand: lane holds w1[hid][k0..k0+7], hid = 32w+16mi+l15, k0 = 32ks+8q
    short8 a1[2][2];
    float4v bias[2];
#pragma unroll
    for (int mi = 0; mi < 2; ++mi) {
        int hid = 32 * w + 16 * mi + l15;
#pragma unroll
        for (int ks = 0; ks < 2; ++ks) {
            int k0 = 32 * ks + 8 * q;
            short8 f = {};
            if (k0 < 48) {
                const float* p = w1 + hid * 48 + k0;
                float4v f0 = *(const float4v*)p;
                float4v f1 = *(const float4v*)(p + 4);
#pragma unroll
                for (int j = 0; j < 4; ++j) {
                    f[j]     = (short)f2bf(f0[j]);
                    f[j + 4] = (short)f2bf(f1[j]);
                }
            }
            a1[mi][ks] = f;
        }
        bias[mi] = *(const float4v*)(b1 + 32 * w + 16 * mi + 4 * q);
    }
    // GEMM2 B-operand: lane holds w2[ch=l15][k0..k0+7], k0 = 32ks+8q
    short8 b2[4];
#pragma unroll
    for (int ks = 0; ks < 4; ++ks) {
        const float* p = w2 + l15 * HN + 32 * ks + 8 * q;
        float4v f0 = *(const float4v*)p;
        float4v f1 = *(const float4v*)(p + 4);
        short8 f;
#pragma unroll
        for (int j = 0; j < 4; ++j) {
            f[j]     = (short)f2bf(f0[j]);
            f[j + 4] = (short)f2bf(f1[j]);
        }
        b2[ks] = f;
    }

    __syncthreads();

    // ---- perception: each thread does 8 channels of one pixel ----
    const int pix = tid & 127;
    const int ty  = pix >> 5, tx = pix & 31;
    const int cb  = (tid >> 7) * 8;    // channel base 0 or 8
    float v[24];
    float ctr[8];
#pragma unroll
    for (int c8 = 0; c8 < 8; ++c8) {
        const float(*s)[34] = u.sx[cb + c8];
        float a00 = s[ty][tx],     a01 = s[ty][tx + 1],     a02 = s[ty][tx + 2];
        float a10 = s[ty + 1][tx], a11 = s[ty + 1][tx + 1], a12 = s[ty + 1][tx + 2];
        float a20 = s[ty + 2][tx], a21 = s[ty + 2][tx + 1], a22 = s[ty + 2][tx + 2];
        float gx = ((a02 - a00) + 2.f * (a12 - a10) + (a22 - a20)) * 0.125f;
        float gy = ((a20 - a00) + 2.f * (a21 - a01) + (a22 - a02)) * 0.125f;
        v[3 * c8]     = a11;
        v[3 * c8 + 1] = gx;
        v[3 * c8 + 2] = gy;
        ctr[c8] = a11;
    }
    {
        uint4v* dst = (uint4v*)&ybuf[pix][3 * cb];
        uint4v t0, t1, t2;
#pragma unroll
        for (int k = 0; k < 4; ++k) {
            t0[k] = pack2(v[2 * k],      v[2 * k + 1]);
            t1[k] = pack2(v[2 * k + 8],  v[2 * k + 9]);
            t2[k] = pack2(v[2 * k + 16], v[2 * k + 17]);
        }
        dst[0] = t0; dst[1] = t1; dst[2] = t2;
        if (cb == 8) {   // zero-pad k = 48..63
            uint4v z = {};
            *(uint4v*)&ybuf[pix][48] = z;
            *(uint4v*)&ybuf[pix][56] = z;
        }
        float4v c0, c1;
#pragma unroll
        for (int k = 0; k < 4; ++k) { c0[k] = ctr[k]; c1[k] = ctr[k + 4]; }
        *(float4v*)&xc[pix][cb]     = c0;
        *(float4v*)&xc[pix][cb + 4] = c1;
    }

    __syncthreads();

    // ---- GEMM1 (transposed): wave w owns hid 32w..32w+31, loops 8 pixel groups ----
#pragma unroll 2
    for (int nt = 0; nt < 8; ++nt) {
        const int prow = 16 * nt + l15;
        short8 y0 = *(const short8*)&ybuf[prow][8 * q];
        short8 y1 = *(const short8*)&ybuf[prow][32 + 8 * q];
#pragma unroll
        for (int mi = 0; mi < 2; ++mi) {
            float4v acc = {};
            acc = __builtin_amdgcn_mfma_f32_16x16x32_bf16(a1[mi][0], y0, acc, 0, 0, 0);
            acc = __builtin_amdgcn_mfma_f32_16x16x32_bf16(a1[mi][1], y1, acc, 0, 0, 0);
            float h0 = fmaxf(acc[0] + bias[mi][0], 0.f);
            float h1 = fmaxf(acc[1] + bias[mi][1], 0.f);
            float h2 = fmaxf(acc[2] + bias[mi][2], 0.f);
            float h3 = fmaxf(acc[3] + bias[mi][3], 0.f);
            uint2v hp;
            hp[0] = pack2(h0, h1);
            hp[1] = pack2(h2, h3);
            // h[pix][hid]: D' rows are hid = 32w+16mi+4q+r (consecutive r) -> one b64
            *(uint2v*)&u.h[prow][32 * w + 16 * mi + 4 * q] = hp;
        }
    }

    __syncthreads();

    // ---- GEMM2: wave w owns pixel tiles 2w, 2w+1 ----
    const float* ub = upd + (size_t)b * HW;
    float* ob = out + (size_t)b * CN * HW;
    float* n3 = xn3 + (size_t)b * HW;
#pragma unroll
    for (int pi = 0; pi < 2; ++pi) {
        const int pt = 2 * w + pi;
        float4v acc = {};
#pragma unroll
        for (int ks = 0; ks < 4; ++ks) {
            short8 hf = *(const short8*)&u.h[16 * pt + l15][32 * ks + 8 * q];
            acc = __builtin_amdgcn_mfma_f32_16x16x32_bf16(hf, b2[ks], acc, 0, 0, 0);
        }
#pragma unroll
        for (int r = 0; r < 4; ++r) {
            const int p2 = 16 * pt + 4 * q + r;
            const float xcv = xc[p2][l15];
            const int i = i0 + (p2 >> 5), j = j0 + (p2 & 31);
            const float uv = ub[i * IMW + j];
            const float mk = (uv <= 0.5f) ? 1.f : 0.f;
            const float xn = fmaf(acc[r], mk, xcv);
            ob[l15 * HW + i * IMW + j] = xn;
            if (l15 == 3) n3[i * IMW + j] = xn;
        }
    }
}

// ---------------- Pass 2: alive masking (unchanged, verified) ----------------
__global__ __launch_bounds__(256) void nca_pass2(
    const float* __restrict__ x, const float* __restrict__ xn3,
    float* __restrict__ out)
{
    __shared__ float s0[10][34];
    __shared__ float s1[10][34];
    const int b  = blockIdx.z;
    const int i0 = blockIdx.y * 8;
    const int j0 = blockIdx.x * 32;
    const int tid = threadIdx.x;
    const float* x3 = x   + ((size_t)b * CN + 3) * HW;
    const float* n3 = xn3 + (size_t)b * HW;

    for (int idx = tid; idx < 10 * 34; idx += 256) {
        int r = idx / 34, col = idx - r * 34;
        int gi = i0 + r - 1, gj = j0 + col - 1;
        bool in = ((unsigned)gi < IMH && (unsigned)gj < IMW);
        s0[r][col] = in ? x3[gi * IMW + gj] : -1e30f;
        s1[r][col] = in ? n3[gi * IMW + gj] : -1e30f;
    }
    __syncthreads();

    const int ty = tid >> 5, tx = tid & 31;
    float m0 = -1e30f, m1 = -1e30f;
#pragma unroll
    for (int di = 0; di < 3; ++di)
#pragma unroll
        for (int dj = 0; dj < 3; ++dj) {
            m0 = fmaxf(m0, s0[ty + di][tx + dj]);
            m1 = fmaxf(m1, s1[ty + di][tx + dj]);
        }
    if (!((m0 > 0.1f) && (m1 > 0.1f))) {
        const int i = i0 + ty, j = j0 + tx;
        float* ob = out + (size_t)b * CN * HW;
#pragma unroll
        for (int c = 0; c < CN; ++c)
            ob[(size_t)c * HW + i * IMW + j] = 0.f;
    }
}

extern "C" void kernel_launch(void* const* d_in, const int* in_sizes, int n_in,
                              void* d_out, int out_size, void* d_ws, size_t ws_size,
                              hipStream_t stream) {
    const float* x   = (const float*)d_in[0];
    const float* upd = (const float*)d_in[1];
    const float* w1  = (const float*)d_in[2];
    const float* b1  = (const float*)d_in[3];
    const float* w2  = (const float*)d_in[4];
    float* out = (float*)d_out;
    float* xn3 = (float*)d_ws;    // 32*256*256 floats = 8 MiB

    dim3 gridA(IMW / 32, IMH / 4, 32);
    nca_mfma<<<gridA, 256, 0, stream>>>(x, upd, w1, b1, w2, out, xn3);
    dim3 gridB(IMW / 32, IMH / 8, 32);
    nca_pass2<<<gridB, 256, 0, stream>>>(x, xn3, out);
}

// Round 3
// 429.570 us; speedup vs baseline: 1.9531x; 1.4711x over previous
//
#include <hip/hip_runtime.h>

#define CN 16
#define HN 128
#define IMH 256
#define IMW 256
#define HW (IMH * IMW)

typedef __attribute__((ext_vector_type(8))) short short8;
typedef __attribute__((ext_vector_type(4))) float float4v;
typedef __attribute__((ext_vector_type(2))) unsigned int uint2v;
typedef __attribute__((ext_vector_type(4))) unsigned int uint4v;

__device__ __forceinline__ unsigned int f2bf(float f) {
    unsigned int u = __builtin_bit_cast(unsigned int, f);
    u += 0x7FFFu + ((u >> 16) & 1u);          // round-to-nearest-even
    return u >> 16;
}
__device__ __forceinline__ unsigned int pack2(float a, float b) {
    return f2bf(a) | (f2bf(b) << 16);
}

// ---------------- Weight prep: fragment-ordered bf16 weights ----------------
// a1f[((mi*2+ks)*64+lane)*8+j] = bf16(w1[16mi+(lane&15)][32ks+8(lane>>4)+j]),
//   with k==48 slot holding b1[hid] (bias folded via y[48]=1.0), k>48 -> 0.
// b2f[(ks*64+lane)*8+j]        = bf16(w2[lane&15][32ks+8(lane>>4)+j])
__global__ void nca_prep(const float* __restrict__ w1, const float* __restrict__ b1,
                         const float* __restrict__ w2,
                         unsigned short* __restrict__ a1f, unsigned short* __restrict__ b2f)
{
    int t = blockIdx.x * 256 + threadIdx.x;
    if (t < 8192) {
        int j = t & 7, lane = (t >> 3) & 63, ks = (t >> 9) & 1, mi = t >> 10;
        int hid = 16 * mi + (lane & 15);
        int k = 32 * ks + 8 * (lane >> 4) + j;
        float v = 0.f;
        if (k < 48) v = w1[hid * 48 + k];
        else if (k == 48) v = b1[hid];
        a1f[t] = (unsigned short)f2bf(v);
    }
    if (t < 2048) {
        int j = t & 7, lane = (t >> 3) & 63, ks = t >> 9;
        b2f[t] = (unsigned short)f2bf(w2[(lane & 15) * HN + 32 * ks + 8 * (lane >> 4) + j]);
    }
}

// ---------------- Kernel A: perception + MFMA MLP + update ----------------
// 128 pixels/block (4x32), 256 threads = 4 waves. Wave w owns pixels 32w..32w+31.
__global__ __launch_bounds__(256, 3) void nca_mfma(
    const float* __restrict__ x, const float* __restrict__ upd,
    const unsigned short* __restrict__ a1f, const unsigned short* __restrict__ b2f,
    float* __restrict__ out, float* __restrict__ xn3, unsigned char* __restrict__ bm)
{
    __shared__ union {
        float sx[6][16][34];               // 13056 B (staging; dead after perception)
        unsigned short hb[4][16][128];     // 16384 B (per-wave h scratch, swizzled)
    } u;
    __shared__ unsigned short ybuf[128][64];   // 16384 B (swizzled, pitch 128B)
    __shared__ float xcT[16][132];             //  8448 B (x centers, transposed)

    const int b   = blockIdx.z;
    const int i0  = blockIdx.y * 4;
    const int j0  = blockIdx.x * 32;
    const int tid = threadIdx.x;
    const int lane = tid & 63, w = tid >> 6;
    const int l15 = lane & 15, q = lane >> 4;
    const float* xb = x + (size_t)b * CN * HW;

    // ---- weight fragment loads (L1/L2-hot; consumed after sync2) ----
    short8 a1[8][2];
#pragma unroll
    for (int mi = 0; mi < 8; ++mi)
#pragma unroll
        for (int ks = 0; ks < 2; ++ks)
            a1[mi][ks] = *(const short8*)(a1f + ((mi * 2 + ks) * 64 + lane) * 8);
    short8 b2[4];
#pragma unroll
    for (int ks = 0; ks < 4; ++ks)
        b2[ks] = *(const short8*)(b2f + (ks * 64 + lane) * 8);

    // ---- stage x tile (+1 halo): layout sx[row 0..5][ch][col 0..33] ----
    const bool interior = (blockIdx.y > 0) & (blockIdx.y < 63) & (blockIdx.x > 0) & (blockIdx.x < 7);
    {
        const int col = tid & 31;
        if (interior) {
            const float* src = xb + (i0 - 1) * IMW + (j0 - 1);
#pragma unroll
            for (int rt = tid >> 5; rt < 96; rt += 8)
                u.sx[rt >> 4][rt & 15][col] = src[(rt & 15) * HW + (rt >> 4) * IMW + col];
            if (tid < 192) {
                int rt = tid >> 1, col2 = 32 + (tid & 1);
                u.sx[rt >> 4][rt & 15][col2] = src[(rt & 15) * HW + (rt >> 4) * IMW + col2];
            }
        } else {
#pragma unroll
            for (int rt = tid >> 5; rt < 96; rt += 8) {
                int rr = rt >> 4, c = rt & 15;
                int gi = i0 + rr - 1, gj = j0 + col - 1;
                float v = 0.f;
                if ((unsigned)gi < IMH && (unsigned)gj < IMW) v = xb[c * HW + gi * IMW + gj];
                u.sx[rr][c][col] = v;
            }
            if (tid < 192) {
                int rt = tid >> 1, col2 = 32 + (tid & 1);
                int rr = rt >> 4, c = rt & 15;
                int gi = i0 + rr - 1, gj = j0 + col2 - 1;
                float v = 0.f;
                if ((unsigned)gi < IMH && (unsigned)gj < IMW) v = xb[c * HW + gi * IMW + gj];
                u.sx[rr][c][col2] = v;
            }
        }
    }
    __syncthreads();

    // ---- perception: thread = (pixel, 8-channel half) ----
    const int pix = tid & 127;
    const int ty  = pix >> 5, tx = pix & 31;
    const int cb  = (tid >> 7) << 3;       // 0 or 8 (wave-uniform)
    float v[24];
#pragma unroll
    for (int c8 = 0; c8 < 8; ++c8) {
        const int c = cb + c8;
        float a00 = u.sx[ty][c][tx],     a01 = u.sx[ty][c][tx + 1],     a02 = u.sx[ty][c][tx + 2];
        float a10 = u.sx[ty + 1][c][tx], a11 = u.sx[ty + 1][c][tx + 1], a12 = u.sx[ty + 1][c][tx + 2];
        float a20 = u.sx[ty + 2][c][tx], a21 = u.sx[ty + 2][c][tx + 1], a22 = u.sx[ty + 2][c][tx + 2];
        v[3 * c8]     = a11;
        v[3 * c8 + 1] = ((a02 - a00) + 2.f * (a12 - a10) + (a22 - a20)) * 0.125f;
        v[3 * c8 + 2] = ((a20 - a00) + 2.f * (a21 - a01) + (a22 - a02)) * 0.125f;
        xcT[c][pix] = a11;
        if (cb == 0 && c8 == 3) {
            // begin-alive: maxpool3 of x ch3 (zero-pad == -inf pad since x >= 0)
            float m0 = fmaxf(fmaxf(fmaxf(a00, a01), fmaxf(a02, a10)),
                             fmaxf(fmaxf(a11, a12), fmaxf(fmaxf(a20, a21), a22)));
            bm[(size_t)b * HW + (i0 + ty) * IMW + (j0 + tx)] = (m0 > 0.1f) ? 1 : 0;
        }
    }
    {
        // pack 24 bf16 -> 3 swizzled 16B groups; cb==8 also writes pad groups 6,7
        unsigned int* yrow = (unsigned int*)&ybuf[pix][0];
        const int gbase = (cb >> 3) * 3;
        const int sw = pix & 7;
#pragma unroll
        for (int t = 0; t < 3; ++t) {
            uint4v g;
#pragma unroll
            for (int k = 0; k < 4; ++k) g[k] = pack2(v[8 * t + 2 * k], v[8 * t + 2 * k + 1]);
            yrow[((gbase + t) ^ sw) << 2] = g[0];   // single uint4 store:
            *(uint4v*)&yrow[((gbase + t) ^ sw) << 2] = g;
        }
        if (cb == 8) {
            uint4v g6 = {0x3F80u, 0u, 0u, 0u};   // y[48] = 1.0 (bias column)
            uint4v g7 = {};
            *(uint4v*)&yrow[(6 ^ sw) << 2] = g6;
            *(uint4v*)&yrow[(7 ^ sw) << 2] = g7;
        }
    }
    __syncthreads();

    // ---- per wave: GEMM1-T (all 128 hid x 16 pix) -> h scratch -> GEMM2 -> epilogue ----
    const float* ub = upd + (size_t)b * HW;
    float* ob = out + (size_t)b * CN * HW;
    float* n3 = xn3 + (size_t)b * HW;
#pragma unroll
    for (int half = 0; half < 2; ++half) {
        const int nt  = 2 * w + half;
        const int row = 16 * nt + l15;
        const unsigned short* yr = &ybuf[row][0];
        const int rsw = row & 7;
        short8 y0 = *(const short8*)(yr + ((q ^ rsw) << 3));
        short8 y1 = *(const short8*)(yr + (((4 + q) ^ rsw) << 3));
        const int hsw = l15 & 7;
#pragma unroll
        for (int mi = 0; mi < 8; ++mi) {
            float4v acc = {};
            acc = __builtin_amdgcn_mfma_f32_16x16x32_bf16(a1[mi][0], y0, acc, 0, 0, 0);
            acc = __builtin_amdgcn_mfma_f32_16x16x32_bf16(a1[mi][1], y1, acc, 0, 0, 0);
            uint2v hp;
            hp[0] = pack2(fmaxf(acc[0], 0.f), fmaxf(acc[1], 0.f));
            hp[1] = pack2(fmaxf(acc[2], 0.f), fmaxf(acc[3], 0.f));
            // logical col 16mi+4q -> group 2mi+(q>>1), offset 4(q&1); XOR-swizzled
            *(uint2v*)&u.hb[w][l15][(((2 * mi + (q >> 1)) ^ hsw) << 3) + ((q & 1) << 2)] = hp;
        }
        float4v acc2 = {};
#pragma unroll
        for (int ks = 0; ks < 4; ++ks) {
            short8 hf = *(const short8*)&u.hb[w][l15][((4 * ks + q) ^ hsw) << 3];
            acc2 = __builtin_amdgcn_mfma_f32_16x16x32_bf16(hf, b2[ks], acc2, 0, 0, 0);
        }
        // epilogue: pixel p2 = 16nt+4q+r, channel = l15; 4 consecutive pixels -> dwordx4
        const int i  = i0 + (nt >> 1);
        const int jb = j0 + ((nt & 1) << 4) + (q << 2);
        float4v xc4 = *(const float4v*)&xcT[l15][16 * nt + 4 * q];
        float4v u4  = *(const float4v*)(ub + i * IMW + jb);
        float4v o;
#pragma unroll
        for (int r = 0; r < 4; ++r)
            o[r] = fmaf(acc2[r], (u4[r] <= 0.5f) ? 1.f : 0.f, xc4[r]);
        *(float4v*)(ob + l15 * HW + i * IMW + jb) = o;
        if (l15 == 3) *(float4v*)(n3 + i * IMW + jb) = o;
    }
}

// ---------------- Pass 2: alive masking ----------------
// alive = bm & (maxpool3(xn3) > 0.1); zero dead pixels in-place (own pixel only).
__global__ __launch_bounds__(256) void nca_pass2(
    const float* __restrict__ xn3, const unsigned char* __restrict__ bm,
    float* __restrict__ out)
{
    __shared__ float s[10][130];
    const int b  = blockIdx.z;
    const int i0 = blockIdx.y * 8;
    const int j0 = blockIdx.x * 128;
    const int tid = threadIdx.x;
    const float* n3 = xn3 + (size_t)b * HW;

    for (int idx = tid; idx < 10 * 130; idx += 256) {
        int r = idx / 130, c = idx - r * 130;
        int gi = i0 + r - 1, gj = j0 + c - 1;
        s[r][c] = ((unsigned)gi < IMH && (unsigned)gj < IMW) ? n3[gi * IMW + gj] : -1e30f;
    }
    __syncthreads();

    const int c = tid & 127, rh = (tid >> 7) * 4;
    const unsigned char* bmp = bm + (size_t)b * HW + (i0 + rh) * IMW + (j0 + c);
    float* ob = out + (size_t)b * CN * HW;
#pragma unroll
    for (int k = 0; k < 4; ++k) {
        const int r = rh + k;
        float m = fmaxf(fmaxf(fmaxf(s[r][c], s[r][c + 1]), fmaxf(s[r][c + 2], s[r + 1][c])),
                        fmaxf(fmaxf(s[r + 1][c + 1], s[r + 1][c + 2]),
                              fmaxf(fmaxf(s[r + 2][c], s[r + 2][c + 1]), s[r + 2][c + 2])));
        if (!((m > 0.1f) && bmp[k * IMW])) {
            const int i = i0 + r, j = j0 + c;
#pragma unroll
            for (int ch = 0; ch < CN; ++ch)
                ob[ch * HW + i * IMW + j] = 0.f;
        }
    }
}

extern "C" void kernel_launch(void* const* d_in, const int* in_sizes, int n_in,
                              void* d_out, int out_size, void* d_ws, size_t ws_size,
                              hipStream_t stream) {
    const float* x   = (const float*)d_in[0];
    const float* upd = (const float*)d_in[1];
    const float* w1  = (const float*)d_in[2];
    const float* b1  = (const float*)d_in[3];
    const float* w2  = (const float*)d_in[4];
    float* out = (float*)d_out;

    char* ws = (char*)d_ws;
    float* xn3          = (float*)ws;                            // 8 MiB
    unsigned char* bmp  = (unsigned char*)(ws + (8u << 20));     // 2 MiB
    unsigned short* a1f = (unsigned short*)(ws + (10u << 20));   // 16 KiB
    unsigned short* b2f = a1f + 8192;                            // 4 KiB

    nca_prep<<<32, 256, 0, stream>>>(w1, b1, w2, a1f, b2f);
    nca_mfma<<<dim3(8, 64, 32), 256, 0, stream>>>(x, upd, a1f, b2f, out, xn3, bmp);
    nca_pass2<<<dim3(2, 32, 32), 256, 0, stream>>>(xn3, bmp, out);
}